// Round 7
// baseline (86.495 us; speedup 1.0000x reference)
//
#include <hip/hip_runtime.h>

#define B_N 8
#define A_N 100000
#define M_N 64
#define ANCH 2
#define TPB 256
#define GX ((A_N + TPB * ANCH - 1) / (TPB * ANCH))   // 196 blocks per batch

// d_ws: ann2[B_N*M_N] float2 {x1,x2} (invalid folded to 1e30), then
// ws_num[B_N*GX], ws_cnt[B_N*GX].

__global__ __launch_bounds__(512) void rl_prep(
    const float* __restrict__ annotations,   // (B, M, 3)
    float2* __restrict__ ann2)
{
    const int t = threadIdx.x;               // 512 == B_N * M_N
    const float* p = annotations + t * 3;
    float x1 = p[0], x2 = p[1], lab = p[2];
    if (lab == -1.0f) { x1 = 1e30f; x2 = 1e30f; }
    // invalid => iw hugely negative, len = 0 => can only "win" while no
    // real overlap exists, and then the 0.5 gate fails anyway.
    ann2[t] = make_float2(x1, x2);
}

__global__ __launch_bounds__(TPB) void rl_main(
    const float* __restrict__ regressions,   // (B, A, 2)
    const float* __restrict__ anchors,       // (1, A, 2)
    const float2* __restrict__ ann2,         // (B*M) compact
    float* __restrict__ ws_num, float* __restrict__ ws_cnt)
{
    __shared__ float2 annl[M_N];             // epilogue random access only
    const int b = blockIdx.y;
    const int tid = threadIdx.x;

    if (tid < M_N) annl[tid] = ann2[b * M_N + tid];
    // no sync yet — hot loop uses wave-uniform (scalar) global loads;
    // LDS is only read in the epilogue, after the sync below.

    const int abase = blockIdx.x * (TPB * ANCH) + tid;

    float a0[ANCH], a1[ANCH], aw[ANCH];
    float iwb0[ANCH], Sb0[ANCH], iwb1[ANCH], Sb1[ANCH];
    int idx0[ANCH], idx1[ANCH];
    bool act[ANCH];
    #pragma unroll
    for (int k = 0; k < ANCH; ++k) {
        int a = abase + k * TPB;
        act[k] = (a < A_N);
        a = act[k] ? a : (A_N - 1);
        const float2 anc = ((const float2*)anchors)[a];
        a0[k] = anc.x; a1[k] = anc.y; aw[k] = anc.y - anc.x;
        iwb0[k] = -1.0f; Sb0[k] = 1.0f; idx0[k] = 0;   // encodes iou = -1
        iwb1[k] = -1.0f; Sb1[k] = 1.0f; idx1[k] = 32;
    }

    // Hot loop, FULLY unrolled: 16 pair-iterations x 2 float4 scalar loads
    // (each float4 = two {x1,x2} annotations; len = x2-x1 derived, validity
    // pre-folded by rl_prep). Full unroll lets the compiler batch-issue
    // s_loads far ahead of use (lgkmcnt pipelining) instead of 4-deep.
    // iou = iw/(S-iw), S = aw+len: monotone in iw/S -> cross-mul compare.
    // Pair tournament halves the loop-carried chain; strict '>' keeps the
    // lower index on ties at every level.
    const float4* annb = (const float4*)(ann2 + b * M_N);  // [32] pairs
    #pragma unroll
    for (int p = 0; p < M_N / 4; ++p) {
        const int m = 2 * p;
        const float4 t01 = annb[p];           // anns m, m+1
        const float4 u01 = annb[p + 16];      // anns m+32, m+33
        const float t0z = t01.y - t01.x, t1z = t01.w - t01.z;
        const float u0z = u01.y - u01.x, u1z = u01.w - u01.z;
        #pragma unroll
        for (int k = 0; k < ANCH; ++k) {
            {
                const float iw0 = fminf(a1[k], t01.y) - fmaxf(a0[k], t01.x);
                const float iw1 = fminf(a1[k], t01.w) - fmaxf(a0[k], t01.z);
                const float S0 = aw[k] + t0z;
                const float S1 = aw[k] + t1z;
                const bool w1 = iw1 * S0 > iw0 * S1;          // tie -> m
                const float iww = w1 ? iw1 : iw0;
                const float Sw  = w1 ? S1  : S0;
                const int   mw  = w1 ? m + 1 : m;
                const bool bet = iww * Sb0[k] > iwb0[k] * Sw; // tie -> best
                iwb0[k] = bet ? iww : iwb0[k];
                Sb0[k]  = bet ? Sw  : Sb0[k];
                idx0[k] = bet ? mw  : idx0[k];
            }
            {
                const float iw0 = fminf(a1[k], u01.y) - fmaxf(a0[k], u01.x);
                const float iw1 = fminf(a1[k], u01.w) - fmaxf(a0[k], u01.z);
                const float S0 = aw[k] + u0z;
                const float S1 = aw[k] + u1z;
                const bool w1 = iw1 * S0 > iw0 * S1;
                const float iww = w1 ? iw1 : iw0;
                const float Sw  = w1 ? S1  : S0;
                const int   mw  = w1 ? m + 33 : m + 32;
                const bool bet = iww * Sb1[k] > iwb1[k] * Sw;
                iwb1[k] = bet ? iww : iwb1[k];
                Sb1[k]  = bet ? Sw  : Sb1[k];
                idx1[k] = bet ? mw  : idx1[k];
            }
        }
    }

    __syncthreads();   // annl[] ready for epilogue random access

    float lsum = 0.0f, lpos = 0.0f;
    #pragma unroll
    for (int k = 0; k < ANCH; ++k) {
        // merge halves: strict '>' keeps half-0 (lower index) on ties
        const bool h1 = iwb1[k] * Sb0[k] > iwb0[k] * Sb1[k];
        const float iwb = h1 ? iwb1[k] : iwb0[k];
        const float Sb  = h1 ? Sb1[k]  : Sb0[k];
        const int   idx = h1 ? idx1[k] : idx0[k];
        // exact gate, reference rounding order
        const float ua  = fmaxf(Sb - iwb, 1e-8f);
        const float iou = iwb / ua;
        if (act[k] && iou >= 0.5f) {
            const float2 g = annl[idx];
            const float gw0 = g.y - g.x;
            const float gcx = g.x + 0.5f * gw0;
            const float gw  = fmaxf(gw0, 1.0f);
            const float acx = a0[k] + 0.5f * aw[k];
            const float tdx = ((gcx - acx) / aw[k]) / 0.1f;
            const float tdw = logf(gw / aw[k]) / 0.2f;
            const float2 rg =
                ((const float2*)regressions)[(size_t)b * A_N + abase + k * TPB];
            const float d0 = fabsf(tdx - rg.x);
            const float d1 = fabsf(tdw - rg.y);
            const float inv9 = 1.0f / 9.0f;
            const float s0 = (d0 <= inv9) ? 4.5f * d0 * d0 : d0 - 0.5f / 9.0f;
            const float s1 = (d1 <= inv9) ? 4.5f * d1 * d1 : d1 - 0.5f / 9.0f;
            lsum += s0 + s1;
            lpos += 1.0f;
        }
    }

    for (int o = 32; o > 0; o >>= 1) {
        lsum += __shfl_down(lsum, o, 64);
        lpos += __shfl_down(lpos, o, 64);
    }
    __shared__ float wsum[TPB / 64], wpos[TPB / 64];
    const int wid  = tid >> 6;
    const int lane = tid & 63;
    if (lane == 0) { wsum[wid] = lsum; wpos[wid] = lpos; }
    __syncthreads();
    if (tid == 0) {
        float s = 0.0f, p = 0.0f;
        #pragma unroll
        for (int w = 0; w < TPB / 64; ++w) { s += wsum[w]; p += wpos[w]; }
        const int slot = b * GX + blockIdx.x;
        ws_num[slot] = s;
        ws_cnt[slot] = p;
    }
}

__global__ __launch_bounds__(512) void rl_final(
    const float* __restrict__ ws_num,
    const float* __restrict__ ws_cnt,
    float* __restrict__ out)
{
    const int wid  = threadIdx.x >> 6;   // wave w handles batch w
    const int lane = threadIdx.x & 63;
    float s = 0.0f, c = 0.0f;
    for (int i = lane; i < GX; i += 64) {
        s += ws_num[wid * GX + i];
        c += ws_cnt[wid * GX + i];
    }
    for (int o = 32; o > 0; o >>= 1) {
        s += __shfl_down(s, o, 64);
        c += __shfl_down(c, o, 64);
    }
    __shared__ float pb[B_N];
    if (lane == 0) {
        const float cnt = 2.0f * c;
        pb[wid] = (cnt > 0.0f) ? s / fmaxf(cnt, 1.0f) : 0.0f;
    }
    __syncthreads();
    if (threadIdx.x == 0) {
        float acc = 0.0f;
        #pragma unroll
        for (int i = 0; i < B_N; ++i) acc += pb[i];
        out[0] = acc * (1.0f / (float)B_N);
    }
}

extern "C" void kernel_launch(void* const* d_in, const int* in_sizes, int n_in,
                              void* d_out, int out_size, void* d_ws, size_t ws_size,
                              hipStream_t stream) {
    const float* regressions = (const float*)d_in[0];
    const float* anchors     = (const float*)d_in[1];
    const float* annotations = (const float*)d_in[2];
    float* out = (float*)d_out;

    float2* ann2  = (float2*)d_ws;                 // [B_N*M_N]
    float*  ws_num = (float*)(ann2 + B_N * M_N);   // [B_N*GX]
    float*  ws_cnt = ws_num + B_N * GX;            // [B_N*GX]

    rl_prep<<<1, 512, 0, stream>>>(annotations, ann2);
    dim3 grid(GX, B_N);
    rl_main<<<grid, TPB, 0, stream>>>(regressions, anchors, ann2,
                                      ws_num, ws_cnt);
    rl_final<<<1, 512, 0, stream>>>(ws_num, ws_cnt, out);
}